// Round 1
// baseline (1825.429 us; speedup 1.0000x reference)
//
#include <hip/hip_runtime.h>

#define PTS 8192          // B*N = 4*2048 points
#define HDIM 512
#define BN_EPS 1e-4f

typedef unsigned short u16;
typedef u16 u16x8 __attribute__((ext_vector_type(8)));
typedef short s16x8 __attribute__((ext_vector_type(8)));
typedef float f32x4 __attribute__((ext_vector_type(4)));

__device__ __forceinline__ float bf2f(u16 u) {
  unsigned x = ((unsigned)u) << 16;
  return __builtin_bit_cast(float, x);
}
__device__ __forceinline__ u16 f2bf(float f) {
  unsigned x = __builtin_bit_cast(unsigned, f);
  x += 0x7fffu + ((x >> 16) & 1u);
  return (u16)(x >> 16);
}
__device__ __forceinline__ float sigf(float x) {
  return __builtin_amdgcn_rcpf(1.f + __expf(-x));
}
__device__ __forceinline__ float fast_tanh(float x) {
  float e = __expf(2.f * x);
  return 1.f - 2.f * __builtin_amdgcn_rcpf(e + 1.f);
}

// ---------------------------------------------------------------- prep
// convert W1,W2 to bf16; BN1 on x -> x_cur; zero lp_state
__global__ void prep_kernel(const float* __restrict__ W1, const float* __restrict__ W2,
                            u16* __restrict__ W1b, u16* __restrict__ W2b,
                            const float* __restrict__ x,
                            const float* __restrict__ m1, const float* __restrict__ v1,
                            const float* __restrict__ lg1, const float* __restrict__ be1,
                            float* __restrict__ x_cur, float* __restrict__ lp_state) {
  int i = blockIdx.x * 256 + threadIdx.x;   // 0 .. 262143
  if (i < 512 * 512) { W1b[i] = f2bf(W1[i]); W2b[i] = f2bf(W2[i]); }
  if (i < PTS * 3) {
    int d = i % 3;
    x_cur[i] = (x[i] - m1[d]) * __expf(lg1[d]) * rsqrtf(v1[d] + BN_EPS) + be1[d];
  }
  if (i < PTS) lp_state[i] = 0.f;
}

// ---------------------------------------------------------------- gates
struct GatesArgs {
  const float* c;
  const float *Wg0, *bg0, *Wb0;
  const float *Wg1, *bg1, *Wb1;
  const float *Wg2, *bg2, *Wb2;
  const float *Wg3, *bg3, *Wb3;
  u16 *G0, *B0, *G1, *B1, *G2, *B2;
  float *G3, *B3;
};
__global__ void gates_kernel(GatesArgs a) {
  __shared__ float cs[16 * 64];
  int pg = blockIdx.x, tid = threadIdx.x;
  for (int i = tid; i < 1024; i += 256) cs[i] = a.c[(size_t)pg * 1024 + i];
  __syncthreads();
  const float* Wgl[3] = {a.Wg0, a.Wg1, a.Wg2};
  const float* Wbl[3] = {a.Wb0, a.Wb1, a.Wb2};
  const float* bgl[3] = {a.bg0, a.bg1, a.bg2};
  u16* Gl[3] = {a.G0, a.G1, a.G2};
  u16* Bl[3] = {a.B0, a.B1, a.B2};
  #pragma unroll 1
  for (int l = 0; l < 3; ++l) {
    #pragma unroll 1
    for (int o = tid; o < 512; o += 256) {
      float wg[64], wb[64];
      const float* wgr = Wgl[l] + o * 65 + 1;
      const float* wbr = Wbl[l] + o * 65 + 1;
      #pragma unroll
      for (int k = 0; k < 64; ++k) { wg[k] = wgr[k]; wb[k] = wbr[k]; }
      float bgv = bgl[l][o];
      #pragma unroll 1
      for (int pp = 0; pp < 16; ++pp) {
        float ag = bgv, ab = 0.f;
        #pragma unroll
        for (int k = 0; k < 64; ++k) {
          float cv = cs[pp * 64 + k];
          ag = fmaf(cv, wg[k], ag);
          ab = fmaf(cv, wb[k], ab);
        }
        size_t p = (size_t)pg * 16 + pp;
        Gl[l][p * 512 + o] = f2bf(ag);
        Bl[l][p * 512 + o] = f2bf(ab);
      }
    }
  }
  if (tid < 48) {
    int o = tid % 3, pp = tid / 3;
    float ag = a.bg3[o], ab = 0.f;
    for (int k = 0; k < 64; ++k) {
      float cv = cs[pp * 64 + k];
      ag = fmaf(cv, a.Wg3[o * 65 + 1 + k], ag);
      ab = fmaf(cv, a.Wb3[o * 65 + 1 + k], ab);
    }
    int p = pg * 16 + pp;
    a.G3[p * 3 + o] = ag;
    a.B3[p * 3 + o] = ab;
  }
}

// ---------------------------------------------------------------- layer0
struct L0Args {
  const float *xin, *W0, *b0, *Wg0, *Wb0, *sqrtT;
  const u16 *G0, *Bc0;
  u16* H1;
  float ts;
};
__global__ void layer0_kernel(L0Args a) {
  int p = blockIdx.x, tid = threadIdx.x;
  float s0 = a.sqrtT[0];
  float dt = s0 * s0 * (1.f / 3.f);
  float t = a.ts * dt;
  float x0 = a.xin[p * 3], x1 = a.xin[p * 3 + 1], x2 = a.xin[p * 3 + 2];
  #pragma unroll
  for (int oi = 0; oi < 2; ++oi) {
    int o = tid + oi * 256;
    float w0 = a.W0[o * 3], w1 = a.W0[o * 3 + 1], w2 = a.W0[o * 3 + 2];
    float u = fmaf(w0, x0, fmaf(w1, x1, w2 * x2)) + a.b0[o];
    float gate = sigf(bf2f(a.G0[(size_t)p * 512 + o]) + t * a.Wg0[o * 65]);
    float bias = bf2f(a.Bc0[(size_t)p * 512 + o]) + t * a.Wb0[o * 65];
    float z = fmaf(u, gate, bias);
    float h = fast_tanh(z);
    float wm = (1.f - h * h) * gate;
    size_t base = (size_t)(p * 4) * 512 + o;
    a.H1[base]        = f2bf(h);
    a.H1[base + 512]  = f2bf(wm * w0);
    a.H1[base + 1024] = f2bf(wm * w1);
    a.H1[base + 1536] = f2bf(wm * w2);
  }
}

// ---------------------------------------------------------------- middle GEMM
// C[m][n] = sum_k A[m][k]*W[n][k]; m = 4*p + stream; fused gate/tanh epilogue
#define LDT 40
struct GemmArgs {
  const u16 *A, *W;
  const float *bvec, *Wg, *Wbm, *sqrtT;
  const u16 *G, *Bc;
  u16* Out;
  float ts;
};
__global__ void gemm_mid(GemmArgs a) {
  __shared__ u16 As[128 * LDT];
  __shared__ u16 Bs[128 * LDT];
  int tid = threadIdx.x;
  int m0 = blockIdx.x * 128, n0 = blockIdx.y * 128;
  int wave = tid >> 6, lane = tid & 63;
  int wm = (wave & 1) * 64, wn = (wave >> 1) * 64;
  int lr = lane & 15, quad = lane >> 4;

  f32x4 acc[4][4];
  #pragma unroll
  for (int i = 0; i < 4; ++i)
    #pragma unroll
    for (int j = 0; j < 4; ++j)
      #pragma unroll
      for (int r = 0; r < 4; ++r) acc[i][j][r] = 0.f;

  int c0 = tid, c1 = tid + 256;
  int row0 = c0 >> 2, cb0 = (c0 & 3) * 8;
  int row1 = c1 >> 2, cb1 = (c1 & 3) * 8;
  const u16* gA0 = a.A + (size_t)(m0 + row0) * 512 + cb0;
  const u16* gA1 = a.A + (size_t)(m0 + row1) * 512 + cb1;
  const u16* gB0 = a.W + (size_t)(n0 + row0) * 512 + cb0;
  const u16* gB1 = a.W + (size_t)(n0 + row1) * 512 + cb1;
  u16* sA0 = &As[row0 * LDT + cb0];
  u16* sA1 = &As[row1 * LDT + cb1];
  u16* sB0 = &Bs[row0 * LDT + cb0];
  u16* sB1 = &Bs[row1 * LDT + cb1];

  for (int k0 = 0; k0 < 512; k0 += 32) {
    u16x8 va0 = *(const u16x8*)(gA0 + k0);
    u16x8 va1 = *(const u16x8*)(gA1 + k0);
    u16x8 vb0 = *(const u16x8*)(gB0 + k0);
    u16x8 vb1 = *(const u16x8*)(gB1 + k0);
    __syncthreads();
    *(u16x8*)sA0 = va0; *(u16x8*)sA1 = va1;
    *(u16x8*)sB0 = vb0; *(u16x8*)sB1 = vb1;
    __syncthreads();
    s16x8 af[4], bfr[4];
    #pragma unroll
    for (int i = 0; i < 4; ++i)
      af[i] = *(const s16x8*)&As[(wm + i * 16 + lr) * LDT + quad * 8];
    #pragma unroll
    for (int j = 0; j < 4; ++j)
      bfr[j] = *(const s16x8*)&Bs[(wn + j * 16 + lr) * LDT + quad * 8];
    #pragma unroll
    for (int i = 0; i < 4; ++i)
      #pragma unroll
      for (int j = 0; j < 4; ++j)
        acc[i][j] = __builtin_amdgcn_mfma_f32_16x16x32_bf16(af[i], bfr[j], acc[i][j], 0, 0, 0);
  }

  float s0 = a.sqrtT[0];
  float dt = s0 * s0 * (1.f / 3.f);
  float t = a.ts * dt;
  #pragma unroll
  for (int j = 0; j < 4; ++j) {
    int n = n0 + wn + j * 16 + lr;
    float bvn = a.bvec[n];
    float wg0 = a.Wg[n * 65], wb0 = a.Wbm[n * 65];
    #pragma unroll
    for (int i = 0; i < 4; ++i) {
      int mrow = m0 + wm + i * 16 + quad * 4;     // = 4*p
      int p = mrow >> 2;
      float gate = sigf(bf2f(a.G[(size_t)p * 512 + n]) + t * wg0);
      float bias = bf2f(a.Bc[(size_t)p * 512 + n]) + t * wb0;
      f32x4 u = acc[i][j];
      float z = fmaf(u[0] + bvn, gate, bias);
      float h = fast_tanh(z);
      float wmf = (1.f - h * h) * gate;
      size_t ob = (size_t)mrow * 512 + n;
      a.Out[ob]        = f2bf(h);
      a.Out[ob + 512]  = f2bf(u[1] * wmf);
      a.Out[ob + 1024] = f2bf(u[2] * wmf);
      a.Out[ob + 1536] = f2bf(u[3] * wmf);
    }
  }
}

// ---------------------------------------------------------------- layer3 + divergence + RK4
struct L3Args {
  const u16* H3;
  const float *W3, *b3, *Wg3, *Wb3, *sqrtT;
  const float *G3, *B3;
  float *x_cur, *x_stage, *kx, *kl, *lp_state;
  float ts;
  int mode;   // 0=k1, 1=k2, 2=k3, 3=k4+final-update
};
__global__ void layer3_kernel(L3Args a) {
  int tid = threadIdx.x;
  int wave = tid >> 6, lane = tid & 63;
  int p = blockIdx.x * 4 + wave;
  float s0 = a.sqrtT[0];
  float dt = s0 * s0 * (1.f / 3.f);
  float t = a.ts * dt;

  const u16* hb = a.H3 + (size_t)(p * 4) * 512 + lane * 8;
  u16x8 vh = *(const u16x8*)(hb);
  u16x8 v0 = *(const u16x8*)(hb + 512);
  u16x8 v1 = *(const u16x8*)(hb + 1024);
  u16x8 v2 = *(const u16x8*)(hb + 1536);

  float fr0 = 0, fr1 = 0, fr2 = 0, dj0 = 0, dj1 = 0, dj2 = 0;
  #pragma unroll
  for (int jj = 0; jj < 8; ++jj) {
    int col = lane * 8 + jj;
    float w0 = a.W3[col], w1 = a.W3[512 + col], w2 = a.W3[1024 + col];
    float hv = bf2f(vh[jj]);
    fr0 = fmaf(hv, w0, fr0);
    fr1 = fmaf(hv, w1, fr1);
    fr2 = fmaf(hv, w2, fr2);
    dj0 = fmaf(bf2f(v0[jj]), w0, dj0);
    dj1 = fmaf(bf2f(v1[jj]), w1, dj1);
    dj2 = fmaf(bf2f(v2[jj]), w2, dj2);
  }
  #pragma unroll
  for (int off = 32; off > 0; off >>= 1) {
    fr0 += __shfl_xor(fr0, off);
    fr1 += __shfl_xor(fr1, off);
    fr2 += __shfl_xor(fr2, off);
    dj0 += __shfl_xor(dj0, off);
    dj1 += __shfl_xor(dj1, off);
    dj2 += __shfl_xor(dj2, off);
  }
  if (lane == 0) {
    float fr[3] = {fr0, fr1, fr2};
    float dj[3] = {dj0, dj1, dj2};
    float dx[3], gate[3];
    #pragma unroll
    for (int r = 0; r < 3; ++r) {
      float u = fr[r] + a.b3[r];
      gate[r] = sigf(a.G3[p * 3 + r] + t * a.Wg3[r * 65]);
      float bias = a.B3[p * 3 + r] + t * a.Wb3[r * 65];
      dx[r] = fmaf(u, gate[r], bias);
    }
    float div = dj[0] * gate[0] + dj[1] * gate[1] + dj[2] * gate[2];
    float klv = -div;
    if (a.mode == 0) {
      #pragma unroll
      for (int r = 0; r < 3; ++r) {
        a.kx[p * 3 + r] = dx[r];
        a.x_stage[p * 3 + r] = a.x_cur[p * 3 + r] + 0.5f * dt * dx[r];
      }
      a.kl[p] = klv;
    } else if (a.mode == 1) {
      #pragma unroll
      for (int r = 0; r < 3; ++r) {
        a.kx[p * 3 + r] += 2.f * dx[r];
        a.x_stage[p * 3 + r] = a.x_cur[p * 3 + r] + 0.5f * dt * dx[r];
      }
      a.kl[p] += 2.f * klv;
    } else if (a.mode == 2) {
      #pragma unroll
      for (int r = 0; r < 3; ++r) {
        a.kx[p * 3 + r] += 2.f * dx[r];
        a.x_stage[p * 3 + r] = a.x_cur[p * 3 + r] + dt * dx[r];
      }
      a.kl[p] += 2.f * klv;
    } else {
      float sc = dt * (1.f / 6.f);
      #pragma unroll
      for (int r = 0; r < 3; ++r)
        a.x_cur[p * 3 + r] += sc * (a.kx[p * 3 + r] + dx[r]);
      a.lp_state[p] += sc * (a.kl[p] + klv);
    }
  }
}

// ---------------------------------------------------------------- finish
__global__ void finish_x(const float* __restrict__ x, const float* __restrict__ m2,
                         const float* __restrict__ v2, const float* __restrict__ lg2,
                         const float* __restrict__ be2, float* __restrict__ out) {
  int i = blockIdx.x * 256 + threadIdx.x;
  if (i < PTS * 3) {
    int d = i % 3;
    out[i] = (x[i] - m2[d]) * __expf(lg2[d]) * rsqrtf(v2[d] + BN_EPS) + be2[d];
  }
}

__global__ void finish_lp(const float* __restrict__ lp_state,
                          const float* __restrict__ v1, const float* __restrict__ lg1,
                          const float* __restrict__ v2, const float* __restrict__ lg2,
                          float* __restrict__ out) {
  int b = blockIdx.x, tid = threadIdx.x;
  float s = 0.f;
  for (int n = tid; n < 2048; n += 256) s += lp_state[b * 2048 + n];
  __shared__ float red[256];
  red[tid] = s;
  __syncthreads();
  for (int w = 128; w > 0; w >>= 1) {
    if (tid < w) red[tid] += red[tid + w];
    __syncthreads();
  }
  if (tid == 0) {
    float ld = 0.f;
    for (int d = 0; d < 3; ++d) {
      ld += lg1[d] - 0.5f * logf(v1[d] + BN_EPS);
      ld += lg2[d] - 0.5f * logf(v2[d] + BN_EPS);
    }
    out[b] = red[0] - 2048.f * ld;
  }
}

// ---------------------------------------------------------------- launch
extern "C" void kernel_launch(void* const* d_in, const int* in_sizes, int n_in,
                              void* d_out, int out_size, void* d_ws, size_t ws_size,
                              hipStream_t stream) {
  const float* x        = (const float*)d_in[0];
  const float* c        = (const float*)d_in[1];
  const float* bn1_mean = (const float*)d_in[2];
  const float* bn1_var  = (const float*)d_in[3];
  const float* bn1_lg   = (const float*)d_in[4];
  const float* bn1_beta = (const float*)d_in[5];
  const float* bn2_mean = (const float*)d_in[6];
  const float* bn2_var  = (const float*)d_in[7];
  const float* bn2_lg   = (const float*)d_in[8];
  const float* bn2_beta = (const float*)d_in[9];
  const float* sqrtT    = (const float*)d_in[10];
  const float* W0  = (const float*)d_in[11];
  const float* b0  = (const float*)d_in[12];
  const float* Wg0 = (const float*)d_in[13];
  const float* bg0 = (const float*)d_in[14];
  const float* Wb0 = (const float*)d_in[15];
  const float* W1  = (const float*)d_in[16];
  const float* b1  = (const float*)d_in[17];
  const float* Wg1 = (const float*)d_in[18];
  const float* bg1 = (const float*)d_in[19];
  const float* Wb1 = (const float*)d_in[20];
  const float* W2  = (const float*)d_in[21];
  const float* b2  = (const float*)d_in[22];
  const float* Wg2 = (const float*)d_in[23];
  const float* bg2 = (const float*)d_in[24];
  const float* Wb2 = (const float*)d_in[25];
  const float* W3  = (const float*)d_in[26];
  const float* b3  = (const float*)d_in[27];
  const float* Wg3 = (const float*)d_in[28];
  const float* bg3 = (const float*)d_in[29];
  const float* Wb3 = (const float*)d_in[30];

  char* base = (char*)d_ws;
  size_t off = 0;
  auto alloc = [&](size_t bytes) -> void* {
    void* pp = base + off;
    off += (bytes + 255) & ~(size_t)255;
    return pp;
  };
  u16* W1b = (u16*)alloc((size_t)512 * 512 * 2);
  u16* W2b = (u16*)alloc((size_t)512 * 512 * 2);
  u16 *G[3], *Bc[3];
  for (int l = 0; l < 3; ++l) {
    G[l]  = (u16*)alloc((size_t)PTS * 512 * 2);
    Bc[l] = (u16*)alloc((size_t)PTS * 512 * 2);
  }
  float* G3f = (float*)alloc((size_t)PTS * 3 * 4);
  float* B3f = (float*)alloc((size_t)PTS * 3 * 4);
  u16* HA = (u16*)alloc((size_t)4 * PTS * 512 * 2);
  u16* HB = (u16*)alloc((size_t)4 * PTS * 512 * 2);
  float* x_cur    = (float*)alloc((size_t)PTS * 3 * 4);
  float* x_stage  = (float*)alloc((size_t)PTS * 3 * 4);
  float* kx       = (float*)alloc((size_t)PTS * 3 * 4);
  float* kl       = (float*)alloc((size_t)PTS * 4);
  float* lp_state = (float*)alloc((size_t)PTS * 4);
  (void)ws_size; (void)in_sizes; (void)n_in; (void)out_size;

  prep_kernel<<<1024, 256, 0, stream>>>(W1, W2, W1b, W2b, x, bn1_mean, bn1_var,
                                        bn1_lg, bn1_beta, x_cur, lp_state);

  GatesArgs ga{c, Wg0, bg0, Wb0, Wg1, bg1, Wb1, Wg2, bg2, Wb2, Wg3, bg3, Wb3,
               G[0], Bc[0], G[1], Bc[1], G[2], Bc[2], G3f, B3f};
  gates_kernel<<<512, 256, 0, stream>>>(ga);

  for (int step = 0; step < 3; ++step) {
    for (int st = 0; st < 4; ++st) {
      float ts = (float)step + (st == 0 ? 0.f : (st == 3 ? 1.f : 0.5f));
      const float* xin = (st == 0) ? x_cur : x_stage;

      L0Args l0{xin, W0, b0, Wg0, Wb0, sqrtT, G[0], Bc[0], HA, ts};
      layer0_kernel<<<PTS, 256, 0, stream>>>(l0);

      GemmArgs g1{HA, W1b, b1, Wg1, Wb1, sqrtT, G[1], Bc[1], HB, ts};
      gemm_mid<<<dim3(256, 4), 256, 0, stream>>>(g1);

      GemmArgs g2{HB, W2b, b2, Wg2, Wb2, sqrtT, G[2], Bc[2], HA, ts};
      gemm_mid<<<dim3(256, 4), 256, 0, stream>>>(g2);

      L3Args l3{HA, W3, b3, Wg3, Wb3, sqrtT, G3f, B3f,
                x_cur, x_stage, kx, kl, lp_state, ts, st};
      layer3_kernel<<<PTS / 4, 256, 0, stream>>>(l3);
    }
  }

  finish_x<<<(PTS * 3 + 255) / 256, 256, 0, stream>>>(x_cur, bn2_mean, bn2_var,
                                                      bn2_lg, bn2_beta, (float*)d_out);
  finish_lp<<<4, 256, 0, stream>>>(lp_state, bn1_var, bn1_lg, bn2_var, bn2_lg,
                                   (float*)d_out + PTS * 3);
}

// Round 2
// 1455.791 us; speedup vs baseline: 1.2539x; 1.2539x over previous
//
#include <hip/hip_runtime.h>

#define PTS 8192          // B*N = 4*2048 points
#define HDIM 512
#define BN_EPS 1e-4f
#define BK 32

typedef unsigned short u16;
typedef u16 u16x8 __attribute__((ext_vector_type(8)));
typedef short s16x8 __attribute__((ext_vector_type(8)));
typedef float f32x4 __attribute__((ext_vector_type(4)));

__device__ __forceinline__ float bf2f(u16 u) {
  unsigned x = ((unsigned)u) << 16;
  return __builtin_bit_cast(float, x);
}
__device__ __forceinline__ u16 f2bf(float f) {
  unsigned x = __builtin_bit_cast(unsigned, f);
  x += 0x7fffu + ((x >> 16) & 1u);
  return (u16)(x >> 16);
}
__device__ __forceinline__ float sigf(float x) {
  return __builtin_amdgcn_rcpf(1.f + __expf(-x));
}
__device__ __forceinline__ float fast_tanh(float x) {
  float e = __expf(2.f * x);
  return 1.f - 2.f * __builtin_amdgcn_rcpf(e + 1.f);
}
__device__ __forceinline__ void gl2lds16(const u16* g, u16* l) {
  __builtin_amdgcn_global_load_lds(
      (const __attribute__((address_space(1))) void*)g,
      (__attribute__((address_space(3))) void*)l, 16, 0, 0);
}

// ---------------------------------------------------------------- prep
struct PrepArgs {
  const float *W1, *W2;
  u16 *W1b, *W2b;
  const float* c;
  u16* cb;
  const float *Wg0, *Wg1, *Wg2, *Wb0, *Wb1, *Wb2;
  const float *bg0, *bg1, *bg2;
  u16* Wpack;          // [6*512][64] bf16 (sections: Wg0,Wg1,Wg2,Wb0,Wb1,Wb2; cols 1..64)
  float* bias_pack;    // [3072]
  const float *x, *m1, *v1, *lg1, *be1;
  float *x_cur, *lp_state;
};
__global__ void prep_kernel(PrepArgs a) {
  int i = blockIdx.x * 256 + threadIdx.x;   // 0 .. 524287
  if (i < 512 * 512) { a.W1b[i] = f2bf(a.W1[i]); a.W2b[i] = f2bf(a.W2[i]); }
  if (i < PTS * 64) a.cb[i] = f2bf(a.c[i]);
  if (i < 6 * 512 * 64) {
    int sec = i >> 15;            // /(512*64)
    int within = i & 32767;
    int o = within >> 6, k = within & 63;
    const float* src[6] = {a.Wg0, a.Wg1, a.Wg2, a.Wb0, a.Wb1, a.Wb2};
    a.Wpack[i] = f2bf(src[sec][o * 65 + 1 + k]);
  }
  if (i < 3072) {
    int sec = i >> 9, o = i & 511;
    const float* bgl[3] = {a.bg0, a.bg1, a.bg2};
    a.bias_pack[i] = (sec < 3) ? bgl[sec][o] : 0.f;
  }
  if (i < PTS * 3) {
    int d = i % 3;
    a.x_cur[i] = (a.x[i] - a.m1[d]) * __expf(a.lg1[d]) * rsqrtf(a.v1[d] + BN_EPS) + a.be1[d];
  }
  if (i < PTS) a.lp_state[i] = 0.f;
}

// ---------------------------------------------------------------- gates GEMM
// GB[sec][p][col] = cb[p][:] . Wpack[sec*512+col][:] + bias_pack[sec*512+col]
// M=8192 (points), N=3072, K=64. 128x128 tiles.
struct GatesGemmArgs {
  const u16 *A, *W;        // cb [8192][64], Wpack [3072][64]
  const float* bias;       // [3072]
  u16* GB;                 // [6][8192][512]
};
__global__ __launch_bounds__(256) void gates_gemm(GatesGemmArgs a) {
  __shared__ u16 As[128 * BK];
  __shared__ u16 Bs[128 * BK];
  int tid = threadIdx.x;
  int m0 = blockIdx.x * 128, n0 = blockIdx.y * 128;
  int wave = tid >> 6, lane = tid & 63;
  int wm = (wave & 1) * 64, wn = (wave >> 1) * 64;
  int lr = lane & 15, quad = lane >> 4;

  int rowS = tid >> 2, colS = (tid & 3) * 8;
  const u16* gA0 = a.A + (size_t)(m0 + rowS) * 64 + colS;
  const u16* gA1 = a.A + (size_t)(m0 + rowS + 64) * 64 + colS;
  const u16* gB0 = a.W + (size_t)(n0 + rowS) * 64 + colS;
  const u16* gB1 = a.W + (size_t)(n0 + rowS + 64) * 64 + colS;
  u16* sA0 = &As[wave * 512];
  u16* sA1 = &As[4096 + wave * 512];
  u16* sB0 = &Bs[wave * 512];
  u16* sB1 = &Bs[4096 + wave * 512];

  f32x4 acc[4][4];
  #pragma unroll
  for (int i = 0; i < 4; ++i)
    #pragma unroll
    for (int j = 0; j < 4; ++j)
      #pragma unroll
      for (int r = 0; r < 4; ++r) acc[i][j][r] = 0.f;

  for (int k0 = 0; k0 < 64; k0 += BK) {
    if (k0) __syncthreads();
    gl2lds16(gA0 + k0, sA0);
    gl2lds16(gA1 + k0, sA1);
    gl2lds16(gB0 + k0, sB0);
    gl2lds16(gB1 + k0, sB1);
    __syncthreads();
    s16x8 af[4], bfr[4];
    #pragma unroll
    for (int i = 0; i < 4; ++i)
      af[i] = *(const s16x8*)&As[(wm + i * 16 + lr) * BK + quad * 8];
    #pragma unroll
    for (int j = 0; j < 4; ++j)
      bfr[j] = *(const s16x8*)&Bs[(wn + j * 16 + lr) * BK + quad * 8];
    #pragma unroll
    for (int i = 0; i < 4; ++i)
      #pragma unroll
      for (int j = 0; j < 4; ++j)
        acc[i][j] = __builtin_amdgcn_mfma_f32_16x16x32_bf16(af[i], bfr[j], acc[i][j], 0, 0, 0);
  }

  #pragma unroll
  for (int j = 0; j < 4; ++j) {
    int n = n0 + wn + j * 16 + lr;
    int sec = n >> 9, col = n & 511;
    float bv = a.bias[n];
    u16* outp = a.GB + (size_t)sec * PTS * 512 + col;
    #pragma unroll
    for (int i = 0; i < 4; ++i) {
      int mrow = m0 + wm + i * 16 + quad * 4;
      #pragma unroll
      for (int r = 0; r < 4; ++r)
        outp[(size_t)(mrow + r) * 512] = f2bf(acc[i][j][r] + bv);
    }
  }
}

// ---------------------------------------------------------------- gates for layer3 (tiny)
__global__ void gates3_kernel(const float* __restrict__ c, const float* __restrict__ Wg3,
                              const float* __restrict__ bg3, const float* __restrict__ Wb3,
                              float* __restrict__ G3, float* __restrict__ B3) {
  int tid = threadIdx.x;
  int wave = tid >> 6, lane = tid & 63;
  int p = blockIdx.x * 4 + wave;
  float cv = c[(size_t)p * 64 + lane];
  float ag[3], ab[3];
  #pragma unroll
  for (int o = 0; o < 3; ++o) {
    ag[o] = cv * Wg3[o * 65 + 1 + lane];
    ab[o] = cv * Wb3[o * 65 + 1 + lane];
  }
  #pragma unroll
  for (int off = 32; off > 0; off >>= 1) {
    #pragma unroll
    for (int o = 0; o < 3; ++o) {
      ag[o] += __shfl_xor(ag[o], off);
      ab[o] += __shfl_xor(ab[o], off);
    }
  }
  if (lane == 0) {
    #pragma unroll
    for (int o = 0; o < 3; ++o) {
      G3[p * 3 + o] = ag[o] + bg3[o];
      B3[p * 3 + o] = ab[o];
    }
  }
}

// ---------------------------------------------------------------- layer0
struct L0Args {
  const float *xin, *W0, *b0, *Wg0, *Wb0, *sqrtT;
  const u16 *G0, *Bc0;
  u16* H1;
  float ts;
};
__global__ void layer0_kernel(L0Args a) {
  int tid = threadIdx.x;
  int wave = tid >> 6, lane = tid & 63;
  int p = blockIdx.x * 4 + wave;
  float s0 = a.sqrtT[0];
  float dt = s0 * s0 * (1.f / 3.f);
  float t = a.ts * dt;
  const float* xr = a.xin + p * 3;
  float x0 = xr[0], x1 = xr[1], x2 = xr[2];
  int o0 = lane * 8;
  u16x8 g8 = *(const u16x8*)(a.G0 + (size_t)p * 512 + o0);
  u16x8 c8 = *(const u16x8*)(a.Bc0 + (size_t)p * 512 + o0);
  u16x8 oh, od0, od1, od2;
  #pragma unroll
  for (int jj = 0; jj < 8; ++jj) {
    int o = o0 + jj;
    float w0 = a.W0[o * 3], w1 = a.W0[o * 3 + 1], w2 = a.W0[o * 3 + 2];
    float u = fmaf(w0, x0, fmaf(w1, x1, w2 * x2)) + a.b0[o];
    float gate = sigf(bf2f(g8[jj]) + t * a.Wg0[o * 65]);
    float bias = bf2f(c8[jj]) + t * a.Wb0[o * 65];
    float z = fmaf(u, gate, bias);
    float h = fast_tanh(z);
    float wm = (1.f - h * h) * gate;
    oh[jj] = f2bf(h);
    od0[jj] = f2bf(wm * w0);
    od1[jj] = f2bf(wm * w1);
    od2[jj] = f2bf(wm * w2);
  }
  size_t base = (size_t)(p * 4) * 512 + o0;
  *(u16x8*)(a.H1 + base) = oh;
  *(u16x8*)(a.H1 + base + 512) = od0;
  *(u16x8*)(a.H1 + base + 1024) = od1;
  *(u16x8*)(a.H1 + base + 1536) = od2;
}

// ---------------------------------------------------------------- middle GEMM
// C[m][n] = sum_k A[m][k]*W[n][k]; m = 4*p + stream; fused gate/tanh epilogue
struct GemmArgs {
  const u16 *A, *W;
  const float *bvec, *Wg, *Wbm, *sqrtT;
  const u16 *G, *Bc;
  u16* Out;
  float ts;
};
__global__ __launch_bounds__(256) void gemm_mid(GemmArgs a) {
  __shared__ u16 As[128 * BK];
  __shared__ u16 Bs[128 * BK];
  int tid = threadIdx.x;
  int m0 = blockIdx.x * 128, n0 = blockIdx.y * 128;
  int wave = tid >> 6, lane = tid & 63;
  int wm = (wave & 1) * 64, wn = (wave >> 1) * 64;
  int lr = lane & 15, quad = lane >> 4;

  int rowS = tid >> 2, colS = (tid & 3) * 8;
  const u16* gA0 = a.A + (size_t)(m0 + rowS) * 512 + colS;
  const u16* gA1 = a.A + (size_t)(m0 + rowS + 64) * 512 + colS;
  const u16* gB0 = a.W + (size_t)(n0 + rowS) * 512 + colS;
  const u16* gB1 = a.W + (size_t)(n0 + rowS + 64) * 512 + colS;
  u16* sA0 = &As[wave * 512];
  u16* sA1 = &As[4096 + wave * 512];
  u16* sB0 = &Bs[wave * 512];
  u16* sB1 = &Bs[4096 + wave * 512];

  f32x4 acc[4][4];
  #pragma unroll
  for (int i = 0; i < 4; ++i)
    #pragma unroll
    for (int j = 0; j < 4; ++j)
      #pragma unroll
      for (int r = 0; r < 4; ++r) acc[i][j][r] = 0.f;

  for (int k0 = 0; k0 < 512; k0 += BK) {
    if (k0) __syncthreads();
    gl2lds16(gA0 + k0, sA0);
    gl2lds16(gA1 + k0, sA1);
    gl2lds16(gB0 + k0, sB0);
    gl2lds16(gB1 + k0, sB1);
    __syncthreads();
    s16x8 af[4], bfr[4];
    #pragma unroll
    for (int i = 0; i < 4; ++i)
      af[i] = *(const s16x8*)&As[(wm + i * 16 + lr) * BK + quad * 8];
    #pragma unroll
    for (int j = 0; j < 4; ++j)
      bfr[j] = *(const s16x8*)&Bs[(wn + j * 16 + lr) * BK + quad * 8];
    #pragma unroll
    for (int i = 0; i < 4; ++i)
      #pragma unroll
      for (int j = 0; j < 4; ++j)
        acc[i][j] = __builtin_amdgcn_mfma_f32_16x16x32_bf16(af[i], bfr[j], acc[i][j], 0, 0, 0);
  }

  float s0 = a.sqrtT[0];
  float dt = s0 * s0 * (1.f / 3.f);
  float t = a.ts * dt;
  #pragma unroll
  for (int j = 0; j < 4; ++j) {
    int n = n0 + wn + j * 16 + lr;
    float bvn = a.bvec[n];
    float wg0 = a.Wg[n * 65], wb0 = a.Wbm[n * 65];
    #pragma unroll
    for (int i = 0; i < 4; ++i) {
      int mrow = m0 + wm + i * 16 + quad * 4;     // = 4*p
      int p = mrow >> 2;
      float gate = sigf(bf2f(a.G[(size_t)p * 512 + n]) + t * wg0);
      float bias = bf2f(a.Bc[(size_t)p * 512 + n]) + t * wb0;
      f32x4 u = acc[i][j];
      float z = fmaf(u[0] + bvn, gate, bias);
      float h = fast_tanh(z);
      float wmf = (1.f - h * h) * gate;
      size_t ob = (size_t)mrow * 512 + n;
      a.Out[ob]        = f2bf(h);
      a.Out[ob + 512]  = f2bf(u[1] * wmf);
      a.Out[ob + 1024] = f2bf(u[2] * wmf);
      a.Out[ob + 1536] = f2bf(u[3] * wmf);
    }
  }
}

// ---------------------------------------------------------------- layer3 + divergence + RK4
struct L3Args {
  const u16* H3;
  const float *W3, *b3, *Wg3, *Wb3, *sqrtT;
  const float *G3, *B3;
  float *x_cur, *x_stage, *kx, *kl, *lp_state;
  float ts;
  int mode;   // 0=k1, 1=k2, 2=k3, 3=k4+final-update
};
__global__ void layer3_kernel(L3Args a) {
  int tid = threadIdx.x;
  int wave = tid >> 6, lane = tid & 63;
  int p = blockIdx.x * 4 + wave;
  float s0 = a.sqrtT[0];
  float dt = s0 * s0 * (1.f / 3.f);
  float t = a.ts * dt;

  const u16* hb = a.H3 + (size_t)(p * 4) * 512 + lane * 8;
  u16x8 vh = *(const u16x8*)(hb);
  u16x8 v0 = *(const u16x8*)(hb + 512);
  u16x8 v1 = *(const u16x8*)(hb + 1024);
  u16x8 v2 = *(const u16x8*)(hb + 1536);

  float fr0 = 0, fr1 = 0, fr2 = 0, dj0 = 0, dj1 = 0, dj2 = 0;
  #pragma unroll
  for (int jj = 0; jj < 8; ++jj) {
    int col = lane * 8 + jj;
    float w0 = a.W3[col], w1 = a.W3[512 + col], w2 = a.W3[1024 + col];
    float hv = bf2f(vh[jj]);
    fr0 = fmaf(hv, w0, fr0);
    fr1 = fmaf(hv, w1, fr1);
    fr2 = fmaf(hv, w2, fr2);
    dj0 = fmaf(bf2f(v0[jj]), w0, dj0);
    dj1 = fmaf(bf2f(v1[jj]), w1, dj1);
    dj2 = fmaf(bf2f(v2[jj]), w2, dj2);
  }
  #pragma unroll
  for (int off = 32; off > 0; off >>= 1) {
    fr0 += __shfl_xor(fr0, off);
    fr1 += __shfl_xor(fr1, off);
    fr2 += __shfl_xor(fr2, off);
    dj0 += __shfl_xor(dj0, off);
    dj1 += __shfl_xor(dj1, off);
    dj2 += __shfl_xor(dj2, off);
  }
  if (lane == 0) {
    float fr[3] = {fr0, fr1, fr2};
    float dj[3] = {dj0, dj1, dj2};
    float dx[3], gate[3];
    #pragma unroll
    for (int r = 0; r < 3; ++r) {
      float u = fr[r] + a.b3[r];
      gate[r] = sigf(a.G3[p * 3 + r] + t * a.Wg3[r * 65]);
      float bias = a.B3[p * 3 + r] + t * a.Wb3[r * 65];
      dx[r] = fmaf(u, gate[r], bias);
    }
    float div = dj[0] * gate[0] + dj[1] * gate[1] + dj[2] * gate[2];
    float klv = -div;
    if (a.mode == 0) {
      #pragma unroll
      for (int r = 0; r < 3; ++r) {
        a.kx[p * 3 + r] = dx[r];
        a.x_stage[p * 3 + r] = a.x_cur[p * 3 + r] + 0.5f * dt * dx[r];
      }
      a.kl[p] = klv;
    } else if (a.mode == 1) {
      #pragma unroll
      for (int r = 0; r < 3; ++r) {
        a.kx[p * 3 + r] += 2.f * dx[r];
        a.x_stage[p * 3 + r] = a.x_cur[p * 3 + r] + 0.5f * dt * dx[r];
      }
      a.kl[p] += 2.f * klv;
    } else if (a.mode == 2) {
      #pragma unroll
      for (int r = 0; r < 3; ++r) {
        a.kx[p * 3 + r] += 2.f * dx[r];
        a.x_stage[p * 3 + r] = a.x_cur[p * 3 + r] + dt * dx[r];
      }
      a.kl[p] += 2.f * klv;
    } else {
      float sc = dt * (1.f / 6.f);
      #pragma unroll
      for (int r = 0; r < 3; ++r)
        a.x_cur[p * 3 + r] += sc * (a.kx[p * 3 + r] + dx[r]);
      a.lp_state[p] += sc * (a.kl[p] + klv);
    }
  }
}

// ---------------------------------------------------------------- finish
__global__ void finish_x(const float* __restrict__ x, const float* __restrict__ m2,
                         const float* __restrict__ v2, const float* __restrict__ lg2,
                         const float* __restrict__ be2, float* __restrict__ out) {
  int i = blockIdx.x * 256 + threadIdx.x;
  if (i < PTS * 3) {
    int d = i % 3;
    out[i] = (x[i] - m2[d]) * __expf(lg2[d]) * rsqrtf(v2[d] + BN_EPS) + be2[d];
  }
}

__global__ void finish_lp(const float* __restrict__ lp_state,
                          const float* __restrict__ v1, const float* __restrict__ lg1,
                          const float* __restrict__ v2, const float* __restrict__ lg2,
                          float* __restrict__ out) {
  int b = blockIdx.x, tid = threadIdx.x;
  float s = 0.f;
  for (int n = tid; n < 2048; n += 256) s += lp_state[b * 2048 + n];
  __shared__ float red[256];
  red[tid] = s;
  __syncthreads();
  for (int w = 128; w > 0; w >>= 1) {
    if (tid < w) red[tid] += red[tid + w];
    __syncthreads();
  }
  if (tid == 0) {
    float ld = 0.f;
    for (int d = 0; d < 3; ++d) {
      ld += lg1[d] - 0.5f * logf(v1[d] + BN_EPS);
      ld += lg2[d] - 0.5f * logf(v2[d] + BN_EPS);
    }
    out[b] = red[0] - 2048.f * ld;
  }
}

// ---------------------------------------------------------------- launch
extern "C" void kernel_launch(void* const* d_in, const int* in_sizes, int n_in,
                              void* d_out, int out_size, void* d_ws, size_t ws_size,
                              hipStream_t stream) {
  const float* x        = (const float*)d_in[0];
  const float* c        = (const float*)d_in[1];
  const float* bn1_mean = (const float*)d_in[2];
  const float* bn1_var  = (const float*)d_in[3];
  const float* bn1_lg   = (const float*)d_in[4];
  const float* bn1_beta = (const float*)d_in[5];
  const float* bn2_mean = (const float*)d_in[6];
  const float* bn2_var  = (const float*)d_in[7];
  const float* bn2_lg   = (const float*)d_in[8];
  const float* bn2_beta = (const float*)d_in[9];
  const float* sqrtT    = (const float*)d_in[10];
  const float* W0  = (const float*)d_in[11];
  const float* b0  = (const float*)d_in[12];
  const float* Wg0 = (const float*)d_in[13];
  const float* bg0 = (const float*)d_in[14];
  const float* Wb0 = (const float*)d_in[15];
  const float* W1  = (const float*)d_in[16];
  const float* b1  = (const float*)d_in[17];
  const float* Wg1 = (const float*)d_in[18];
  const float* bg1 = (const float*)d_in[19];
  const float* Wb1 = (const float*)d_in[20];
  const float* W2  = (const float*)d_in[21];
  const float* b2  = (const float*)d_in[22];
  const float* Wg2 = (const float*)d_in[23];
  const float* bg2 = (const float*)d_in[24];
  const float* Wb2 = (const float*)d_in[25];
  const float* W3  = (const float*)d_in[26];
  const float* b3  = (const float*)d_in[27];
  const float* Wg3 = (const float*)d_in[28];
  const float* bg3 = (const float*)d_in[29];
  const float* Wb3 = (const float*)d_in[30];

  char* base = (char*)d_ws;
  size_t off = 0;
  auto alloc = [&](size_t bytes) -> void* {
    void* pp = base + off;
    off += (bytes + 255) & ~(size_t)255;
    return pp;
  };
  u16* W1b = (u16*)alloc((size_t)512 * 512 * 2);
  u16* W2b = (u16*)alloc((size_t)512 * 512 * 2);
  u16* cb  = (u16*)alloc((size_t)PTS * 64 * 2);
  u16* Wpack = (u16*)alloc((size_t)6 * 512 * 64 * 2);
  float* bias_pack = (float*)alloc((size_t)3072 * 4);
  u16* GB = (u16*)alloc((size_t)6 * PTS * 512 * 2);
  const size_t SZ = (size_t)PTS * 512;
  u16* G[3]  = {GB, GB + SZ, GB + 2 * SZ};
  u16* Bc[3] = {GB + 3 * SZ, GB + 4 * SZ, GB + 5 * SZ};
  float* G3f = (float*)alloc((size_t)PTS * 3 * 4);
  float* B3f = (float*)alloc((size_t)PTS * 3 * 4);
  u16* HA = (u16*)alloc((size_t)4 * PTS * 512 * 2);
  u16* HB = (u16*)alloc((size_t)4 * PTS * 512 * 2);
  float* x_cur    = (float*)alloc((size_t)PTS * 3 * 4);
  float* x_stage  = (float*)alloc((size_t)PTS * 3 * 4);
  float* kx       = (float*)alloc((size_t)PTS * 3 * 4);
  float* kl       = (float*)alloc((size_t)PTS * 4);
  float* lp_state = (float*)alloc((size_t)PTS * 4);
  (void)ws_size; (void)in_sizes; (void)n_in; (void)out_size;

  PrepArgs pa{W1, W2, W1b, W2b, c, cb, Wg0, Wg1, Wg2, Wb0, Wb1, Wb2,
              bg0, bg1, bg2, Wpack, bias_pack, x, bn1_mean, bn1_var,
              bn1_lg, bn1_beta, x_cur, lp_state};
  prep_kernel<<<2048, 256, 0, stream>>>(pa);

  GatesGemmArgs gg{cb, Wpack, bias_pack, GB};
  gates_gemm<<<dim3(64, 24), 256, 0, stream>>>(gg);
  gates3_kernel<<<PTS / 4, 256, 0, stream>>>(c, Wg3, bg3, Wb3, G3f, B3f);

  for (int step = 0; step < 3; ++step) {
    for (int st = 0; st < 4; ++st) {
      float ts = (float)step + (st == 0 ? 0.f : (st == 3 ? 1.f : 0.5f));
      const float* xin = (st == 0) ? x_cur : x_stage;

      L0Args l0{xin, W0, b0, Wg0, Wb0, sqrtT, G[0], Bc[0], HA, ts};
      layer0_kernel<<<PTS / 4, 256, 0, stream>>>(l0);

      GemmArgs g1{HA, W1b, b1, Wg1, Wb1, sqrtT, G[1], Bc[1], HB, ts};
      gemm_mid<<<dim3(256, 4), 256, 0, stream>>>(g1);

      GemmArgs g2{HB, W2b, b2, Wg2, Wb2, sqrtT, G[2], Bc[2], HA, ts};
      gemm_mid<<<dim3(256, 4), 256, 0, stream>>>(g2);

      L3Args l3{HA, W3, b3, Wg3, Wb3, sqrtT, G3f, B3f,
                x_cur, x_stage, kx, kl, lp_state, ts, st};
      layer3_kernel<<<PTS / 4, 256, 0, stream>>>(l3);
    }
  }

  finish_x<<<(PTS * 3 + 255) / 256, 256, 0, stream>>>(x_cur, bn2_mean, bn2_var,
                                                      bn2_lg, bn2_beta, (float*)d_out);
  finish_lp<<<4, 256, 0, stream>>>(lp_state, bn1_var, bn1_lg, bn2_var, bn2_lg,
                                   (float*)d_out + PTS * 3);
}